// Round 6
// baseline (1962.761 us; speedup 1.0000x reference)
//
#include <hip/hip_runtime.h>
#include <hip/hip_bf16.h>

#define BATCH 4
#define SEQ   4096
#define BS_TOK (BATCH*SEQ)   // 16384 rows
#define EMB   512
#define NH    8
#define HD    64
#define FF    2048
#define NL    6

typedef unsigned short u16;
typedef __attribute__((ext_vector_type(8))) short bf16x8;
typedef __attribute__((ext_vector_type(4))) float f32x4;

__device__ __forceinline__ float bf2f(u16 u) {
    union { unsigned int i; float f; } x; x.i = ((unsigned int)u) << 16; return x.f;
}
__device__ __forceinline__ u16 f2bf(float f) {
    __hip_bfloat16 b = __float2bfloat16(f);
    return *(u16*)&b;
}
__device__ __forceinline__ float gelu_tanh(float x) {
    float x3 = x * x * x;
    return 0.5f * x * (1.f + tanhf(0.7978845608028654f * (x + 0.044715f * x3)));
}
__device__ __forceinline__ void store_out(float* p, float v) { *p = v; }
__device__ __forceinline__ void store_out(u16* p, float v) { *p = f2bf(v); }

__device__ __forceinline__ void gl_lds16(const void* g, void* l) {
    __builtin_amdgcn_global_load_lds(
        (__attribute__((address_space(1))) void*)g,
        (__attribute__((address_space(3))) void*)l, 16, 0, 0);
}

// ---------------------------------------------------------------------------
__global__ __launch_bounds__(128) void embed_kernel(
        const int* __restrict__ tok, const float* __restrict__ emb,
        float* __restrict__ X, float* __restrict__ maskf) {
    int row = blockIdx.x;
    int t = threadIdx.x;
    int id = tok[row];
    if (t == 0) maskf[row] = (id > 0) ? 1.f : 0.f;
    int s = row & (SEQ - 1);
    int e0 = t * 4;
    float4 u = *(const float4*)(emb + (size_t)id * EMB + e0);
    float vals[4] = { u.x, u.y, u.z, u.w };
    float out[4];
#pragma unroll
    for (int j = 0; j < 4; ++j) {
        int ee = e0 + j;
        int i = ee >> 1;
        float div = expf(-0.035977892078031970f * (float)i);
        float ang = (float)s * div;
        float pe = (ee & 1) ? cosf(ang) : sinf(ang);
        out[j] = vals[j] + pe;
    }
    *(float4*)(X + (size_t)row * EMB + e0) = make_float4(out[0], out[1], out[2], out[3]);
}

// ---------------------------------------------------------------------------
template<typename OUT>
__global__ __launch_bounds__(256) void ln_kernel(
        const float* __restrict__ X, const float* __restrict__ sc,
        const float* __restrict__ bi, OUT* __restrict__ Y) {
    int row = blockIdx.x, t = threadIdx.x;
    const float* x = X + (size_t)row * EMB;
    float a = x[t], b = x[t + 256];
    float s = a + b, q = a * a + b * b;
#pragma unroll
    for (int off = 32; off; off >>= 1) {
        s += __shfl_xor(s, off);
        q += __shfl_xor(q, off);
    }
    __shared__ float ss[4], qq[4];
    int w = t >> 6;
    if ((t & 63) == 0) { ss[w] = s; qq[w] = q; }
    __syncthreads();
    s = ss[0] + ss[1] + ss[2] + ss[3];
    q = qq[0] + qq[1] + qq[2] + qq[3];
    float mu = s * (1.f / 512.f);
    float var = q * (1.f / 512.f) - mu * mu;
    float rstd = rsqrtf(var + 1e-6f);
    float y0 = (a - mu) * rstd * sc[t] + bi[t];
    float y1 = (b - mu) * rstd * sc[t + 256] + bi[t + 256];
    store_out(&Y[(size_t)row * EMB + t], y0);
    store_out(&Y[(size_t)row * EMB + t + 256], y1);
}

// ---------------------------------------------------------------------------
// Weight transpose + bf16 cast: W[K][N] f32 -> WT[N][K] bf16; z picks source
// ---------------------------------------------------------------------------
__global__ __launch_bounds__(256) void transpose_w(
        const float* __restrict__ W0, const float* __restrict__ W1,
        const float* __restrict__ W2, const float* __restrict__ W3,
        u16* __restrict__ WT, int K, int N) {
    const float* W = (blockIdx.z == 0) ? W0 : (blockIdx.z == 1) ? W1
                   : (blockIdx.z == 2) ? W2 : W3;
    u16* dst = WT + (size_t)blockIdx.z * K * N;
    __shared__ u16 tile[32][33];
    int n0 = blockIdx.x * 32, k0 = blockIdx.y * 32;
    int tx = threadIdx.x & 31, ty = threadIdx.x >> 5;
#pragma unroll
    for (int u = 0; u < 4; ++u)
        tile[ty + u * 8][tx] = f2bf(W[(size_t)(k0 + ty + u * 8) * N + n0 + tx]);
    __syncthreads();
#pragma unroll
    for (int u = 0; u < 4; ++u)
        dst[(size_t)(n0 + ty + u * 8) * K + k0 + tx] = tile[tx][ty + u * 8];
}

// ---------------------------------------------------------------------------
// MFMA bf16 GEMM: C[M,.] = epi(A[M,K]bf16 . BT[N,K]bf16^T)
// Tile 128(M) x 128(N), 4 waves each own a 64x64 quadrant (acc 4x4 of
// 16x16x32).  K-loop: T4 counted-vmcnt pipeline, 3 buffers of BK=32 (48 KB
// LDS -> 3 blocks/CU), ONE raw s_barrier per step, vmcnt NEVER drained to 0
// in the loop (only at the last step):
//   prologue: stage(0); stage(1)
//   step kt:  vmcnt(4) [stage kt landed; kt+1 stays in flight]; s_barrier;
//             stage((kt+2)%3)  [target = buffer read at kt-1, done by barrier];
//             ds_read frags; 16 MFMA.
// Invariants: read-source landed (each wave passes own vmcnt(4) pre-barrier);
// stage target never concurrently read (3-buffer distance + barrier);
// compiler memory fences around the barrier (bare builtin is IntrNoMem).
// XCD-chunked block swizzle (bijective when nwg%8==0): FETCH 69->21 MB (r5).
// OP: 0=none, 1=gelu, 3=fused-qkv (seg by col0: q=phi, k=phi*mask, v=none).
// epi: (+bias) -> OP -> (+residual), residual loads staged before stores
// (residual may alias C; per-element single-owner load-then-store).
// ---------------------------------------------------------------------------
template<int OP, typename OUT>
__global__ __launch_bounds__(256, 2) void mfma_gemm(
        const u16* __restrict__ A, const u16* __restrict__ BT,
        const float* __restrict__ bias, const float* __restrict__ rowscale,
        const float* __restrict__ residual, OUT* __restrict__ C,
        int K, int lda, int ldb, int ldc) {
    __shared__ u16 As[3][128 * 32];   // buffer bb: [128 rows][32 k] (64B rows)
    __shared__ u16 Bs[3][128 * 32];
    int tid = threadIdx.x;
    int wid = tid >> 6, lane = tid & 63;
    // XCD swizzle (bijective when nwg % 8 == 0; else identity)
    int nwg = gridDim.x * gridDim.y;
    int lin = blockIdx.y * gridDim.x + blockIdx.x;
    int swz = (nwg & 7) ? lin : ((lin & 7) * (nwg >> 3) + (lin >> 3));
    int bx = swz % gridDim.x, by = swz / gridDim.x;
    int row0 = by * 128, col0 = bx * 128;
    int wm = (wid & 1) * 64, wn = (wid >> 1) * 64;
    int quad = lane >> 4, l16 = lane & 15;

    f32x4 acc[4][4];
#pragma unroll
    for (int i = 0; i < 4; ++i)
#pragma unroll
        for (int j = 0; j < 4; ++j)
#pragma unroll
            for (int r = 0; r < 4; ++r) acc[i][j][r] = 0.f;

    // staging: issue i covers rows i*64..i*64+63; wave w covers rows w*16 +
    // lane/4, 16B piece (lane&3).  LDS dest = wave-uniform base + lane*16.
    // 4 gl_lds16 per thread per stage -> vmcnt +4/stage (per-wave counter).
    int rsub = lane >> 2;
    int koff = (lane & 3) * 8;
    const u16* gA = A  + (size_t)(row0 + wid * 16 + rsub) * lda + koff;
    const u16* gB = BT + (size_t)(col0 + wid * 16 + rsub) * ldb + koff;

    auto stage = [&](int bb, int kk) {
        u16* lA = As[bb] + wid * 512;
        u16* lB = Bs[bb] + wid * 512;
#pragma unroll
        for (int i = 0; i < 2; ++i) {
            gl_lds16(gA + (size_t)(i * 64) * lda + kk, lA + i * 2048);
            gl_lds16(gB + (size_t)(i * 64) * ldb + kk, lB + i * 2048);
        }
    };

    int nt = K >> 5;           // BK=32 steps (K=512 -> 16, K=1024 -> 32)
    stage(0, 0);
    stage(1, 32);
    for (int kt = 0; kt < nt; ++kt) {
        int cur = kt % 3;
        if (kt < nt - 1) asm volatile("s_waitcnt vmcnt(4)" ::: "memory");
        else             asm volatile("s_waitcnt vmcnt(0)" ::: "memory");
        __builtin_amdgcn_s_barrier();
        asm volatile("" ::: "memory");
        if (kt + 2 < nt) stage((kt + 2) % 3, (kt + 2) * 32);
        bf16x8 af[4], bfv[4];
#pragma unroll
        for (int i = 0; i < 4; ++i)
            af[i] = *(const bf16x8*)(As[cur] + (wm + i * 16 + l16) * 32 + quad * 8);
#pragma unroll
        for (int j = 0; j < 4; ++j)
            bfv[j] = *(const bf16x8*)(Bs[cur] + (wn + j * 16 + l16) * 32 + quad * 8);
#pragma unroll
        for (int i = 0; i < 4; ++i)
#pragma unroll
            for (int j = 0; j < 4; ++j)
                acc[i][j] = __builtin_amdgcn_mfma_f32_16x16x32_bf16(af[i], bfv[j], acc[i][j], 0, 0, 0);
    }

    // epilogue: D mapping col = lane&15, row = quad*4 + reg (m89-verified)
    int seg = col0 >> 9;   // OP3: 0=q 1=k 2=v (128-col tile never straddles)
    float bc[4];
#pragma unroll
    for (int j = 0; j < 4; ++j)
        bc[j] = bias ? bias[col0 + wn + j * 16 + l16] : 0.f;
#pragma unroll
    for (int i = 0; i < 4; ++i) {
        // stage residual loads for this i-group (16 loads in flight, no
        // interleaved stores -> no alias-serialization)
        float res[4][4];
        if (residual) {
#pragma unroll
            for (int r = 0; r < 4; ++r) {
                size_t rb = (size_t)(row0 + wm + i * 16 + quad * 4 + r) * ldc + col0 + wn;
#pragma unroll
                for (int j = 0; j < 4; ++j)
                    res[r][j] = residual[rb + j * 16 + l16];
            }
        }
#pragma unroll
        for (int r = 0; r < 4; ++r) {
            int row = row0 + wm + i * 16 + quad * 4 + r;
            float rsv = (OP == 3 && seg == 1) ? rowscale[row] : 1.f;
            size_t rb = (size_t)row * ldc + col0 + wn;
#pragma unroll
            for (int j = 0; j < 4; ++j) {
                float val = acc[i][j][r] + bc[j];
                if (OP == 1) val = gelu_tanh(val);
                if (OP == 3 && seg < 2) val = fmaxf(val, 0.f) + 1e-3f;
                if (OP == 3 && seg == 1) val *= rsv;
                size_t idx = rb + j * 16 + l16;
                if (residual) val += res[r][j];
                store_out(&C[idx], val);
            }
        }
    }
}

// ---------------------------------------------------------------------------
// MFMA kv-reduce: kv[bh][m][d] = sum_s PK[s][m]*V[s][d]; z[bh][m] = sum_s PK[s][m]
//   = GEMM PK^T . V with K = S.  Block: 4 waves, each owns a 32m x 32d quadrant
// (acc 2x2 of 16x16x32).  Per 32-s step: stage PK/V tiles [32][68] u16 padded,
// gather fragments with 8 scalar LDS reads each (operands need s-contiguous at
// fixed col), 4 MFMA/wave.  z folded in as ones-operand MFMA on waves 0/1.
// Prefetch next tile into regs before compute (hides L2 latency).
// grid = (32 bh, SEQ/256); atomics into zeroed KV/Z.
// ---------------------------------------------------------------------------
__global__ __launch_bounds__(256) void kv_reduce_mfma(
        const u16* __restrict__ PK, const u16* __restrict__ V,
        float* __restrict__ KV, float* __restrict__ Z, int ld) {
    __shared__ __align__(16) u16 pks[32][68];
    __shared__ __align__(16) u16 vvs[32][68];
    int bh = blockIdx.x;
    int b = bh >> 3, hh = bh & 7;
    int cc = blockIdx.y;
    int t = threadIdx.x;
    int wid = t >> 6, lane = t & 63;
    int quad = lane >> 4, l16 = lane & 15;
    int wm = (wid & 1) * 32, wd = (wid >> 1) * 32;

    f32x4 acc[2][2];
    f32x4 zacc[2];
#pragma unroll
    for (int i = 0; i < 2; ++i) {
#pragma unroll
        for (int j = 0; j < 2; ++j)
#pragma unroll
            for (int r = 0; r < 4; ++r) acc[i][j][r] = 0.f;
#pragma unroll
        for (int r = 0; r < 4; ++r) zacc[i][r] = 0.f;
    }
    bf16x8 ones;
#pragma unroll
    for (int e = 0; e < 8; ++e) ones[e] = (short)0x3F80;   // bf16 1.0

    // staging assignment: thread t -> row s_l = t>>3, 8-col piece mo = (t&7)*8
    int s_l = t >> 3, mo = (t & 7) * 8;
    const u16* gP = PK + (size_t)(b * SEQ + cc * 256 + s_l) * ld + hh * 64 + mo;
    const u16* gV = V  + (size_t)(b * SEQ + cc * 256 + s_l) * ld + hh * 64 + mo;
    ushort4 p0 = *(const ushort4*)gP;
    ushort4 p1 = *(const ushort4*)(gP + 4);
    ushort4 q0 = *(const ushort4*)gV;
    ushort4 q1 = *(const ushort4*)(gV + 4);

    for (int st = 0; st < 8; ++st) {
        *(ushort4*)&pks[s_l][mo]     = p0;
        *(ushort4*)&pks[s_l][mo + 4] = p1;
        *(ushort4*)&vvs[s_l][mo]     = q0;
        *(ushort4*)&vvs[s_l][mo + 4] = q1;
        __syncthreads();
        if (st < 7) {   // prefetch next tile (hides L2 latency under compute)
            gP += (size_t)32 * ld;  gV += (size_t)32 * ld;
            p0 = *(const ushort4*)gP;  p1 = *(const ushort4*)(gP + 4);
            q0 = *(const ushort4*)gV;  q1 = *(const ushort4*)(gV + 4);
        }
        bf16x8 af[2], bfv[2];
#pragma unroll
        for (int i = 0; i < 2; ++i) {
#pragma unroll
            for (int e = 0; e < 8; ++e) {
                af[i][e]  = (short)pks[quad * 8 + e][wm + i * 16 + l16];
                bfv[i][e] = (short)vvs[quad * 8 + e][wd + i * 16 + l16];
            }
        }
#pragma unroll
        for (int i = 0; i < 2; ++i)
#pragma unroll
            for (int j = 0; j < 2; ++j)
                acc[i][j] = __builtin_amdgcn_mfma_f32_16x16x32_bf16(af[i], bfv[j], acc[i][j], 0, 0, 0);
        if (wid < 2) {   // z: waves 0 (m 0..31) and 1 (m 32..63)
            zacc[0] = __builtin_amdgcn_mfma_f32_16x16x32_bf16(af[0], ones, zacc[0], 0, 0, 0);
            zacc[1] = __builtin_amdgcn_mfma_f32_16x16x32_bf16(af[1], ones, zacc[1], 0, 0, 0);
        }
        __syncthreads();
    }

    // epilogue: D col = l16, row = quad*4 + r
#pragma unroll
    for (int i = 0; i < 2; ++i)
#pragma unroll
        for (int j = 0; j < 2; ++j)
#pragma unroll
            for (int r = 0; r < 4; ++r)
                atomicAdd(&KV[((size_t)bh * 64 + wm + i * 16 + quad * 4 + r) * 64
                              + wd + j * 16 + l16], acc[i][j][r]);
    if (wid < 2 && l16 == 0) {
#pragma unroll
        for (int i = 0; i < 2; ++i)
#pragma unroll
            for (int r = 0; r < 4; ++r)
                atomicAdd(&Z[(size_t)bh * 64 + wm + i * 16 + quad * 4 + r], zacc[i][r]);
    }
}

// ---------------------------------------------------------------------------
// out[b,s,h,d] = (phi_q . kv[:,d]) / (phi_q . z);  PQ strided by ld
// ---------------------------------------------------------------------------
__global__ __launch_bounds__(256) void attn_out2(
        const u16* __restrict__ PQ, const float* __restrict__ KV,
        const float* __restrict__ Z, u16* __restrict__ O, int ld) {
    __shared__ float kvT[64 * 65];
    __shared__ float zsh[64];
    __shared__ float phs[4][72];
    int hh = blockIdx.y;
    int row0 = blockIdx.x * 32;
    int b = row0 >> 12;
    int bh = b * NH + hh;
    int t = threadIdx.x;
    const float* kvg = KV + (size_t)bh * 4096;
#pragma unroll
    for (int u = 0; u < 16; ++u) {
        int idx = u * 256 + t;
        kvT[(idx & 63) * 65 + (idx >> 6)] = kvg[idx];
    }
    if (t < 64) zsh[t] = Z[(size_t)bh * 64 + t];
    __syncthreads();
    int wid = t >> 6, lane = t & 63;
    const float* kvrow = kvT + lane * 65;
    for (int rr = 0; rr < 8; ++rr) {
        int row = row0 + wid * 8 + rr;
        float p = bf2f(PQ[(size_t)row * ld + hh * 64 + lane]);
        float d = p * zsh[lane];
#pragma unroll
        for (int off = 32; off; off >>= 1) d += __shfl_xor(d, off);
        d = fmaxf(d, 1e-20f);
        phs[wid][lane] = p;
        float acc = 0.f;
#pragma unroll
        for (int mm = 0; mm < 64; ++mm)
            acc = fmaf(phs[wid][mm], kvrow[mm], acc);
        O[(size_t)row * EMB + hh * 64 + lane] = f2bf(acc / d);
    }
}

// ---------------------------------------------------------------------------
extern "C" void kernel_launch(void* const* d_in, const int* in_sizes, int n_in,
                              void* d_out, int out_size, void* d_ws, size_t ws_size,
                              hipStream_t stream) {
    (void)in_sizes; (void)n_in; (void)out_size; (void)ws_size;
    const int*   tok  = (const int*)d_in[0];
    const float* emb  = (const float*)d_in[1];
    const float* ln1s = (const float*)d_in[2];
    const float* ln1b = (const float*)d_in[3];
    const float* wq   = (const float*)d_in[4];
    const float* wk   = (const float*)d_in[5];
    const float* wv   = (const float*)d_in[6];
    const float* wo   = (const float*)d_in[7];
    const float* ln2s = (const float*)d_in[8];
    const float* ln2b = (const float*)d_in[9];
    const float* w1   = (const float*)d_in[10];
    const float* b1   = (const float*)d_in[11];
    const float* w2   = (const float*)d_in[12];
    const float* b2   = (const float*)d_in[13];
    const float* lnfs = (const float*)d_in[14];
    const float* lnfb = (const float*)d_in[15];

    char* ws = (char*)d_ws;
    const size_t MB = 1024 * 1024;
    float* x    = (float*)(ws);                    // [BS,512] f32 residual, 0-32MB
    u16*   h    = (u16*)(ws + 32 * MB);            // [BS,512] bf16, 32-48
    u16*   qkv  = (u16*)(ws + 48 * MB);            // [BS,1536] bf16, 48-96
    u16*   m    = qkv;                             // [BS,1024] FFN chunk aliases qkv
    float* kv   = (float*)(ws + 96 * MB);          // [B,H,64,64]
    float* z    = kv + BATCH * NH * HD * HD;
    float* maskf = (float*)(ws + 96 * MB + 768 * 1024);   // [BS]
    u16*   wt   = (u16*)(ws + 97 * MB);            // qkvoT: 4x[512][512] (2MB)
    u16*   w1t  = (u16*)(ws + 99 * MB);            // w1T [2048][512] (2MB)
    u16*   w2t  = (u16*)(ws + 101 * MB);           // w2T [512][2048] (2MB)

    embed_kernel<<<BS_TOK, 128, 0, stream>>>(tok, emb, x, maskf);

    const size_t WSTEP = (size_t)EMB * EMB;
    dim3 gQKV(12, BS_TOK / 128);   // N=1536, nwg=1536 (%8==0)
    dim3 gN512(4, BS_TOK / 128);   // N=512,  nwg=512
    dim3 gN1024(8, BS_TOK / 128);  // N=1024, nwg=1024

    for (int l = 0; l < NL; ++l) {
        ln_kernel<u16><<<BS_TOK, 256, 0, stream>>>(x, ln1s + l * EMB, ln1b + l * EMB, h);
        // transpose wq,wk,wv,wo -> wt slots 0..3
        transpose_w<<<dim3(16, 16, 4), 256, 0, stream>>>(
            wq + l * WSTEP, wk + l * WSTEP, wv + l * WSTEP, wo + l * WSTEP, wt, EMB, EMB);
        // fused qkv: q=phi, k=phi*mask, v=plain -> qkv [BS,1536]
        mfma_gemm<3, u16><<<gQKV, 256, 0, stream>>>(
            h, wt, nullptr, maskf, nullptr, qkv, EMB, EMB, EMB, 1536);

        hipMemsetAsync(kv, 0, (size_t)(BATCH * NH * HD * HD + BATCH * NH * HD) * sizeof(float), stream);
        kv_reduce_mfma<<<dim3(BATCH * NH, SEQ / 256), 256, 0, stream>>>(qkv + 512, qkv + 1024, kv, z, 1536);
        attn_out2<<<dim3(BS_TOK / 32, NH), 256, 0, stream>>>(qkv, kv, z, h, 1536);

        // x = x + attn_out @ wo
        mfma_gemm<0, float><<<gN512, 256, 0, stream>>>(
            h, wt + 3 * WSTEP, nullptr, nullptr, x, x, EMB, EMB, EMB, EMB);

        ln_kernel<u16><<<BS_TOK, 256, 0, stream>>>(x, ln2s + l * EMB, ln2b + l * EMB, h);
        const float* w1l = w1 + (size_t)l * EMB * FF;
        const float* w2l = w2 + (size_t)l * FF * EMB;
        const float* b1l = b1 + (size_t)l * FF;
        const float* b2l = b2 + (size_t)l * EMB;
        transpose_w<<<dim3(64, 16, 1), 256, 0, stream>>>(w1l, w1l, w1l, w1l, w1t, EMB, FF);  // [2048][512]
        transpose_w<<<dim3(16, 64, 1), 256, 0, stream>>>(w2l, w2l, w2l, w2l, w2t, FF, EMB);  // [512][2048]
        for (int c = 0; c < 2; ++c) {
            // m = gelu(h @ w1_chunk + b1_chunk)   [BS,1024]
            mfma_gemm<1, u16><<<gN1024, 256, 0, stream>>>(
                h, w1t + (size_t)c * 1024 * EMB, b1l + c * 1024, nullptr, nullptr, m,
                EMB, EMB, EMB, 1024);
            // x += m @ w2_chunk (+b2 on chunk 0)
            mfma_gemm<0, float><<<gN512, 256, 0, stream>>>(
                m, w2t + (size_t)c * 1024, (c == 0 ? b2l : nullptr), nullptr, x, x,
                1024, 1024, FF, EMB);
        }
    }

    ln_kernel<float><<<BS_TOK, 256, 0, stream>>>(x, lnfs, lnfb, (float*)d_out);
}

// Round 7
// 1847.861 us; speedup vs baseline: 1.0622x; 1.0622x over previous
//
#include <hip/hip_runtime.h>
#include <hip/hip_bf16.h>

#define BATCH 4
#define SEQ   4096
#define BS_TOK (BATCH*SEQ)   // 16384 rows
#define EMB   512
#define NH    8
#define HD    64
#define FF    2048
#define NL    6

typedef unsigned short u16;
typedef __attribute__((ext_vector_type(8))) short bf16x8;
typedef __attribute__((ext_vector_type(4))) float f32x4;

__device__ __forceinline__ float bf2f(u16 u) {
    union { unsigned int i; float f; } x; x.i = ((unsigned int)u) << 16; return x.f;
}
__device__ __forceinline__ u16 f2bf(float f) {
    __hip_bfloat16 b = __float2bfloat16(f);
    return *(u16*)&b;
}
// gelu(x) = 0.5x(1+tanh(z)), z=0.79788456(x+0.044715x^3)  ==  x / (1+e^{-2z})
// (exact algebraic identity; 1 v_exp_f32 + ~6 VALU vs libm tanhf ~25+ ops)
__device__ __forceinline__ float gelu_fast(float x) {
    float e = __expf(x * (-1.5957691216057308f - 0.0713548162726009f * x * x));
    return x * __builtin_amdgcn_rcpf(1.f + e);
}
__device__ __forceinline__ void store_out(float* p, float v) { *p = v; }
__device__ __forceinline__ void store_out(u16* p, float v) { *p = f2bf(v); }
__device__ __forceinline__ void store_pair(float* p, float a, float b) {
    *(float2*)p = make_float2(a, b);
}
__device__ __forceinline__ void store_pair(u16* p, float a, float b) {
    unsigned int u = ((unsigned int)f2bf(b) << 16) | (unsigned int)f2bf(a);
    *(unsigned int*)p = u;
}

__device__ __forceinline__ void gl_lds16(const void* g, void* l) {
    __builtin_amdgcn_global_load_lds(
        (__attribute__((address_space(1))) void*)g,
        (__attribute__((address_space(3))) void*)l, 16, 0, 0);
}

// ---------------------------------------------------------------------------
__global__ __launch_bounds__(128) void embed_kernel(
        const int* __restrict__ tok, const float* __restrict__ emb,
        float* __restrict__ X, float* __restrict__ maskf) {
    int row = blockIdx.x;
    int t = threadIdx.x;
    int id = tok[row];
    if (t == 0) maskf[row] = (id > 0) ? 1.f : 0.f;
    int s = row & (SEQ - 1);
    int e0 = t * 4;
    float4 u = *(const float4*)(emb + (size_t)id * EMB + e0);
    float vals[4] = { u.x, u.y, u.z, u.w };
    float out[4];
#pragma unroll
    for (int j = 0; j < 4; ++j) {
        int ee = e0 + j;
        int i = ee >> 1;
        float div = expf(-0.035977892078031970f * (float)i);
        float ang = (float)s * div;
        float pe = (ee & 1) ? cosf(ang) : sinf(ang);
        out[j] = vals[j] + pe;
    }
    *(float4*)(X + (size_t)row * EMB + e0) = make_float4(out[0], out[1], out[2], out[3]);
}

// ---------------------------------------------------------------------------
// LN row kernel, vectorized (G13): float2 loads of x/sc/bi, packed 4B stores.
// ---------------------------------------------------------------------------
template<typename OUT>
__global__ __launch_bounds__(256) void ln_kernel(
        const float* __restrict__ X, const float* __restrict__ sc,
        const float* __restrict__ bi, OUT* __restrict__ Y) {
    int row = blockIdx.x, t = threadIdx.x;
    const float* x = X + (size_t)row * EMB;
    float2 v = *(const float2*)(x + 2 * t);
    float a = v.x, b = v.y;
    float s = a + b, q = a * a + b * b;
#pragma unroll
    for (int off = 32; off; off >>= 1) {
        s += __shfl_xor(s, off);
        q += __shfl_xor(q, off);
    }
    __shared__ float ss[4], qq[4];
    int w = t >> 6;
    if ((t & 63) == 0) { ss[w] = s; qq[w] = q; }
    __syncthreads();
    s = ss[0] + ss[1] + ss[2] + ss[3];
    q = qq[0] + qq[1] + qq[2] + qq[3];
    float mu = s * (1.f / 512.f);
    float var = q * (1.f / 512.f) - mu * mu;
    float rstd = rsqrtf(var + 1e-6f);
    float2 scv = *(const float2*)(sc + 2 * t);
    float2 biv = *(const float2*)(bi + 2 * t);
    float y0 = (a - mu) * rstd * scv.x + biv.x;
    float y1 = (b - mu) * rstd * scv.y + biv.y;
    store_pair(&Y[(size_t)row * EMB + 2 * t], y0, y1);
}

// ---------------------------------------------------------------------------
// Weight transpose + bf16 cast: W[K][N] f32 -> WT[N][K] bf16; z picks source
// ---------------------------------------------------------------------------
__global__ __launch_bounds__(256) void transpose_w(
        const float* __restrict__ W0, const float* __restrict__ W1,
        const float* __restrict__ W2, const float* __restrict__ W3,
        u16* __restrict__ WT, int K, int N) {
    const float* W = (blockIdx.z == 0) ? W0 : (blockIdx.z == 1) ? W1
                   : (blockIdx.z == 2) ? W2 : W3;
    u16* dst = WT + (size_t)blockIdx.z * K * N;
    __shared__ u16 tile[32][33];
    int n0 = blockIdx.x * 32, k0 = blockIdx.y * 32;
    int tx = threadIdx.x & 31, ty = threadIdx.x >> 5;
#pragma unroll
    for (int u = 0; u < 4; ++u)
        tile[ty + u * 8][tx] = f2bf(W[(size_t)(k0 + ty + u * 8) * N + n0 + tx]);
    __syncthreads();
#pragma unroll
    for (int u = 0; u < 4; ++u)
        dst[(size_t)(n0 + ty + u * 8) * K + k0 + tx] = tile[tx][ty + u * 8];
}

// ---------------------------------------------------------------------------
// MFMA bf16 GEMM: C[M,.] = epi(A[M,K]bf16 . BT[N,K]bf16^T)
// Tile 128(M) x 128(N), 4 waves each own a 64x64 quadrant (acc 4x4 of
// 16x16x32).  K-loop: stage-early double-buffer, BK=32 per buffer (32 KB
// LDS), issue next tile's global_load_lds BEFORE compute, one __syncthreads
// per step.  [r6 lesson: counted-vmcnt 3-buffer raw-barrier pipeline
// REGRESSED (VALUBusy 28->43%, runtime %3 addressing + order-pinning defeats
// compiler scheduling; T4 needs the 8-phase structure to pay -- regime gate).
// This is the reverted, measured-best 2-phase config (r5: 1843 us).]
// XCD-chunked block swizzle (bijective when nwg%8==0): FETCH 69->21 MB (r5).
// OP: 0=none, 1=gelu, 3=fused-qkv (seg by col0: q=phi, k=phi*mask, v=none).
// epi: (+bias) -> OP -> (+residual), residual loads staged before stores
// (residual may alias C; per-element single-owner load-then-store).
// ---------------------------------------------------------------------------
template<int OP, typename OUT>
__global__ __launch_bounds__(256, 2) void mfma_gemm(
        const u16* __restrict__ A, const u16* __restrict__ BT,
        const float* __restrict__ bias, const float* __restrict__ rowscale,
        const float* __restrict__ residual, OUT* __restrict__ C,
        int K, int lda, int ldb, int ldc) {
    __shared__ u16 As[2][128 * 32];   // buffer bb: [128 rows][32 k] (64B rows)
    __shared__ u16 Bs[2][128 * 32];
    int tid = threadIdx.x;
    int wid = tid >> 6, lane = tid & 63;
    // XCD swizzle (bijective when nwg % 8 == 0; else identity)
    int nwg = gridDim.x * gridDim.y;
    int lin = blockIdx.y * gridDim.x + blockIdx.x;
    int swz = (nwg & 7) ? lin : ((lin & 7) * (nwg >> 3) + (lin >> 3));
    int bx = swz % gridDim.x, by = swz / gridDim.x;
    int row0 = by * 128, col0 = bx * 128;
    int wm = (wid & 1) * 64, wn = (wid >> 1) * 64;
    int quad = lane >> 4, l16 = lane & 15;

    f32x4 acc[4][4];
#pragma unroll
    for (int i = 0; i < 4; ++i)
#pragma unroll
        for (int j = 0; j < 4; ++j)
#pragma unroll
            for (int r = 0; r < 4; ++r) acc[i][j][r] = 0.f;

    // staging: issue i covers rows i*64..i*64+63; wave w covers rows w*16 +
    // lane/4, 16B piece (lane&3).  LDS dest = wave-uniform base + lane*16.
    int rsub = lane >> 2;
    int koff = (lane & 3) * 8;
    const u16* gA = A  + (size_t)(row0 + wid * 16 + rsub) * lda + koff;
    const u16* gB = BT + (size_t)(col0 + wid * 16 + rsub) * ldb + koff;

    auto stage = [&](int bb, int kk) {
        u16* lA = As[bb] + wid * 512;
        u16* lB = Bs[bb] + wid * 512;
#pragma unroll
        for (int i = 0; i < 2; ++i) {
            gl_lds16(gA + (size_t)(i * 64) * lda + kk, lA + i * 2048);
            gl_lds16(gB + (size_t)(i * 64) * ldb + kk, lB + i * 2048);
        }
    };

    int nt = K >> 5;           // BK=32 steps
    stage(0, 0);
    __syncthreads();           // drain prologue loads
    for (int t = 0; t < nt; ++t) {
        int cur = t & 1;
        if (t + 1 < nt) stage(cur ^ 1, (t + 1) * 32);   // issue next tile EARLY
        bf16x8 af[4], bfv[4];
#pragma unroll
        for (int i = 0; i < 4; ++i)
            af[i] = *(const bf16x8*)(As[cur] + (wm + i * 16 + l16) * 32 + quad * 8);
#pragma unroll
        for (int j = 0; j < 4; ++j)
            bfv[j] = *(const bf16x8*)(Bs[cur] + (wn + j * 16 + l16) * 32 + quad * 8);
#pragma unroll
        for (int i = 0; i < 4; ++i)
#pragma unroll
            for (int j = 0; j < 4; ++j)
                acc[i][j] = __builtin_amdgcn_mfma_f32_16x16x32_bf16(af[i], bfv[j], acc[i][j], 0, 0, 0);
        __syncthreads();       // one barrier/step: drains next-tile vmcnt,
                               // fences LDS reuse for the other buffer
    }

    // epilogue: D mapping col = lane&15, row = quad*4 + reg (m89-verified)
    int seg = col0 >> 9;   // OP3: 0=q 1=k 2=v (128-col tile never straddles)
    float bc[4];
#pragma unroll
    for (int j = 0; j < 4; ++j)
        bc[j] = bias ? bias[col0 + wn + j * 16 + l16] : 0.f;
#pragma unroll
    for (int i = 0; i < 4; ++i) {
        // stage residual loads for this i-group (16 loads in flight, no
        // interleaved stores -> no alias-serialization)
        float res[4][4];
        if (residual) {
#pragma unroll
            for (int r = 0; r < 4; ++r) {
                size_t rb = (size_t)(row0 + wm + i * 16 + quad * 4 + r) * ldc + col0 + wn;
#pragma unroll
                for (int j = 0; j < 4; ++j)
                    res[r][j] = residual[rb + j * 16 + l16];
            }
        }
#pragma unroll
        for (int r = 0; r < 4; ++r) {
            int row = row0 + wm + i * 16 + quad * 4 + r;
            float rsv = (OP == 3 && seg == 1) ? rowscale[row] : 1.f;
            size_t rb = (size_t)row * ldc + col0 + wn;
#pragma unroll
            for (int j = 0; j < 4; ++j) {
                float val = acc[i][j][r] + bc[j];
                if (OP == 1) val = gelu_fast(val);
                if (OP == 3 && seg < 2) val = fmaxf(val, 0.f) + 1e-3f;
                if (OP == 3 && seg == 1) val *= rsv;
                size_t idx = rb + j * 16 + l16;
                if (residual) val += res[r][j];
                store_out(&C[idx], val);
            }
        }
    }
}

// ---------------------------------------------------------------------------
// MFMA kv-reduce: kv[bh][m][d] = sum_s PK[s][m]*V[s][d]; z[bh][m] = sum_s PK[s][m]
//   = GEMM PK^T . V with K = S.  Block: 4 waves, each owns a 32m x 32d quadrant
// (acc 2x2 of 16x16x32).  Per 32-s step: stage PK/V tiles [32][68] u16 padded,
// gather fragments with 8 scalar LDS reads each (operands need s-contiguous at
// fixed col), 4 MFMA/wave.  z folded in as ones-operand MFMA on waves 0/1.
// Prefetch next tile into regs before compute (hides L2 latency).
// grid = (32 bh, SEQ/256); atomics into zeroed KV/Z.
// ---------------------------------------------------------------------------
__global__ __launch_bounds__(256) void kv_reduce_mfma(
        const u16* __restrict__ PK, const u16* __restrict__ V,
        float* __restrict__ KV, float* __restrict__ Z, int ld) {
    __shared__ __align__(16) u16 pks[32][68];
    __shared__ __align__(16) u16 vvs[32][68];
    int bh = blockIdx.x;
    int b = bh >> 3, hh = bh & 7;
    int cc = blockIdx.y;
    int t = threadIdx.x;
    int wid = t >> 6, lane = t & 63;
    int quad = lane >> 4, l16 = lane & 15;
    int wm = (wid & 1) * 32, wd = (wid >> 1) * 32;

    f32x4 acc[2][2];
    f32x4 zacc[2];
#pragma unroll
    for (int i = 0; i < 2; ++i) {
#pragma unroll
        for (int j = 0; j < 2; ++j)
#pragma unroll
            for (int r = 0; r < 4; ++r) acc[i][j][r] = 0.f;
#pragma unroll
        for (int r = 0; r < 4; ++r) zacc[i][r] = 0.f;
    }
    bf16x8 ones;
#pragma unroll
    for (int e = 0; e < 8; ++e) ones[e] = (short)0x3F80;   // bf16 1.0

    // staging assignment: thread t -> row s_l = t>>3, 8-col piece mo = (t&7)*8
    int s_l = t >> 3, mo = (t & 7) * 8;
    const u16* gP = PK + (size_t)(b * SEQ + cc * 256 + s_l) * ld + hh * 64 + mo;
    const u16* gV = V  + (size_t)(b * SEQ + cc * 256 + s_l) * ld + hh * 64 + mo;
    ushort4 p0 = *(const ushort4*)gP;
    ushort4 p1 = *(const ushort4*)(gP + 4);
    ushort4 q0 = *(const ushort4*)gV;
    ushort4 q1 = *(const ushort4*)(gV + 4);

    for (int st = 0; st < 8; ++st) {
        *(ushort4*)&pks[s_l][mo]     = p0;
        *(ushort4*)&pks[s_l][mo + 4] = p1;
        *(ushort4*)&vvs[s_l][mo]     = q0;
        *(ushort4*)&vvs[s_l][mo + 4] = q1;
        __syncthreads();
        if (st < 7) {   // prefetch next tile (hides L2 latency under compute)
            gP += (size_t)32 * ld;  gV += (size_t)32 * ld;
            p0 = *(const ushort4*)gP;  p1 = *(const ushort4*)(gP + 4);
            q0 = *(const ushort4*)gV;  q1 = *(const ushort4*)(gV + 4);
        }
        bf16x8 af[2], bfv[2];
#pragma unroll
        for (int i = 0; i < 2; ++i) {
#pragma unroll
            for (int e = 0; e < 8; ++e) {
                af[i][e]  = (short)pks[quad * 8 + e][wm + i * 16 + l16];
                bfv[i][e] = (short)vvs[quad * 8 + e][wd + i * 16 + l16];
            }
        }
#pragma unroll
        for (int i = 0; i < 2; ++i)
#pragma unroll
            for (int j = 0; j < 2; ++j)
                acc[i][j] = __builtin_amdgcn_mfma_f32_16x16x32_bf16(af[i], bfv[j], acc[i][j], 0, 0, 0);
        if (wid < 2) {   // z: waves 0 (m 0..31) and 1 (m 32..63)
            zacc[0] = __builtin_amdgcn_mfma_f32_16x16x32_bf16(af[0], ones, zacc[0], 0, 0, 0);
            zacc[1] = __builtin_amdgcn_mfma_f32_16x16x32_bf16(af[1], ones, zacc[1], 0, 0, 0);
        }
        __syncthreads();
    }

    // epilogue: D col = l16, row = quad*4 + r
#pragma unroll
    for (int i = 0; i < 2; ++i)
#pragma unroll
        for (int j = 0; j < 2; ++j)
#pragma unroll
            for (int r = 0; r < 4; ++r)
                atomicAdd(&KV[((size_t)bh * 64 + wm + i * 16 + quad * 4 + r) * 64
                              + wd + j * 16 + l16], acc[i][j][r]);
    if (wid < 2 && l16 == 0) {
#pragma unroll
        for (int i = 0; i < 2; ++i)
#pragma unroll
            for (int r = 0; r < 4; ++r)
                atomicAdd(&Z[(size_t)bh * 64 + wm + i * 16 + quad * 4 + r], zacc[i][r]);
    }
}

// ---------------------------------------------------------------------------
// out[b,s,h,d] = (phi_q . kv[:,d]) / (phi_q . z);  PQ strided by ld
// ---------------------------------------------------------------------------
__global__ __launch_bounds__(256) void attn_out2(
        const u16* __restrict__ PQ, const float* __restrict__ KV,
        const float* __restrict__ Z, u16* __restrict__ O, int ld) {
    __shared__ float kvT[64 * 65];
    __shared__ float zsh[64];
    __shared__ float phs[4][72];
    int hh = blockIdx.y;
    int row0 = blockIdx.x * 32;
    int b = row0 >> 12;
    int bh = b * NH + hh;
    int t = threadIdx.x;
    const float* kvg = KV + (size_t)bh * 4096;
#pragma unroll
    for (int u = 0; u < 16; ++u) {
        int idx = u * 256 + t;
        kvT[(idx & 63) * 65 + (idx >> 6)] = kvg[idx];
    }
    if (t < 64) zsh[t] = Z[(size_t)bh * 64 + t];
    __syncthreads();
    int wid = t >> 6, lane = t & 63;
    const float* kvrow = kvT + lane * 65;
    for (int rr = 0; rr < 8; ++rr) {
        int row = row0 + wid * 8 + rr;
        float p = bf2f(PQ[(size_t)row * ld + hh * 64 + lane]);
        float d = p * zsh[lane];
#pragma unroll
        for (int off = 32; off; off >>= 1) d += __shfl_xor(d, off);
        d = fmaxf(d, 1e-20f);
        phs[wid][lane] = p;
        float acc = 0.f;
#pragma unroll
        for (int mm = 0; mm < 64; ++mm)
            acc = fmaf(phs[wid][mm], kvrow[mm], acc);
        O[(size_t)row * EMB + hh * 64 + lane] = f2bf(acc / d);
    }
}

// ---------------------------------------------------------------------------
extern "C" void kernel_launch(void* const* d_in, const int* in_sizes, int n_in,
                              void* d_out, int out_size, void* d_ws, size_t ws_size,
                              hipStream_t stream) {
    (void)in_sizes; (void)n_in; (void)out_size; (void)ws_size;
    const int*   tok  = (const int*)d_in[0];
    const float* emb  = (const float*)d_in[1];
    const float* ln1s = (const float*)d_in[2];
    const float* ln1b = (const float*)d_in[3];
    const float* wq   = (const float*)d_in[4];
    const float* wk   = (const float*)d_in[5];
    const float* wv   = (const float*)d_in[6];
    const float* wo   = (const float*)d_in[7];
    const float* ln2s = (const float*)d_in[8];
    const float* ln2b = (const float*)d_in[9];
    const float* w1   = (const float*)d_in[10];
    const float* b1   = (const float*)d_in[11];
    const float* w2   = (const float*)d_in[12];
    const float* b2   = (const float*)d_in[13];
    const float* lnfs = (const float*)d_in[14];
    const float* lnfb = (const float*)d_in[15];

    char* ws = (char*)d_ws;
    const size_t MB = 1024 * 1024;
    float* x    = (float*)(ws);                    // [BS,512] f32 residual, 0-32MB
    u16*   h    = (u16*)(ws + 32 * MB);            // [BS,512] bf16, 32-48
    u16*   qkv  = (u16*)(ws + 48 * MB);            // [BS,1536] bf16, 48-96
    u16*   m    = qkv;                             // [BS,1024] FFN chunk aliases qkv
    float* kv   = (float*)(ws + 96 * MB);          // [B,H,64,64]
    float* z    = kv + BATCH * NH * HD * HD;
    float* maskf = (float*)(ws + 96 * MB + 768 * 1024);   // [BS]
    u16*   wt   = (u16*)(ws + 97 * MB);            // qkvoT: 4x[512][512] (2MB)
    u16*   w1t  = (u16*)(ws + 99 * MB);            // w1T [2048][512] (2MB)
    u16*   w2t  = (u16*)(ws + 101 * MB);           // w2T [512][2048] (2MB)

    embed_kernel<<<BS_TOK, 128, 0, stream>>>(tok, emb, x, maskf);

    const size_t WSTEP = (size_t)EMB * EMB;
    dim3 gQKV(12, BS_TOK / 128);   // N=1536, nwg=1536 (%8==0)
    dim3 gN512(4, BS_TOK / 128);   // N=512,  nwg=512
    dim3 gN1024(8, BS_TOK / 128);  // N=1024, nwg=1024

    for (int l = 0; l < NL; ++l) {
        ln_kernel<u16><<<BS_TOK, 256, 0, stream>>>(x, ln1s + l * EMB, ln1b + l * EMB, h);
        // transpose wq,wk,wv,wo -> wt slots 0..3
        transpose_w<<<dim3(16, 16, 4), 256, 0, stream>>>(
            wq + l * WSTEP, wk + l * WSTEP, wv + l * WSTEP, wo + l * WSTEP, wt, EMB, EMB);
        // fused qkv: q=phi, k=phi*mask, v=plain -> qkv [BS,1536]
        mfma_gemm<3, u16><<<gQKV, 256, 0, stream>>>(
            h, wt, nullptr, maskf, nullptr, qkv, EMB, EMB, EMB, 1536);

        hipMemsetAsync(kv, 0, (size_t)(BATCH * NH * HD * HD + BATCH * NH * HD) * sizeof(float), stream);
        kv_reduce_mfma<<<dim3(BATCH * NH, SEQ / 256), 256, 0, stream>>>(qkv + 512, qkv + 1024, kv, z, 1536);
        attn_out2<<<dim3(BS_TOK / 32, NH), 256, 0, stream>>>(qkv, kv, z, h, 1536);

        // x = x + attn_out @ wo
        mfma_gemm<0, float><<<gN512, 256, 0, stream>>>(
            h, wt + 3 * WSTEP, nullptr, nullptr, x, x, EMB, EMB, EMB, EMB);

        ln_kernel<u16><<<BS_TOK, 256, 0, stream>>>(x, ln2s + l * EMB, ln2b + l * EMB, h);
        const float* w1l = w1 + (size_t)l * EMB * FF;
        const float* w2l = w2 + (size_t)l * FF * EMB;
        const float* b1l = b1 + (size_t)l * FF;
        const float* b2l = b2 + (size_t)l * EMB;
        transpose_w<<<dim3(64, 16, 1), 256, 0, stream>>>(w1l, w1l, w1l, w1l, w1t, EMB, FF);  // [2048][512]
        transpose_w<<<dim3(16, 64, 1), 256, 0, stream>>>(w2l, w2l, w2l, w2l, w2t, FF, EMB);  // [512][2048]
        for (int c = 0; c < 2; ++c) {
            // m = gelu(h @ w1_chunk + b1_chunk)   [BS,1024]
            mfma_gemm<1, u16><<<gN1024, 256, 0, stream>>>(
                h, w1t + (size_t)c * 1024 * EMB, b1l + c * 1024, nullptr, nullptr, m,
                EMB, EMB, EMB, 1024);
            // x += m @ w2_chunk (+b2 on chunk 0)
            mfma_gemm<0, float><<<gN512, 256, 0, stream>>>(
                m, w2t + (size_t)c * 1024, (c == 0 ? b2l : nullptr), nullptr, x, x,
                1024, 1024, FF, EMB);
        }
    }

    ln_kernel<float><<<BS_TOK, 256, 0, stream>>>(x, lnfs, lnfb, (float*)d_out);
}

// Round 8
// 1650.315 us; speedup vs baseline: 1.1893x; 1.1197x over previous
//
#include <hip/hip_runtime.h>
#include <hip/hip_bf16.h>

#define BATCH 4
#define SEQ   4096
#define BS_TOK (BATCH*SEQ)   // 16384 rows
#define EMB   512
#define NH    8
#define HD    64
#define FF    2048
#define NL    6

typedef unsigned short u16;
typedef __attribute__((ext_vector_type(8))) short bf16x8;
typedef __attribute__((ext_vector_type(4))) float f32x4;

__device__ __forceinline__ float bf2f(u16 u) {
    union { unsigned int i; float f; } x; x.i = ((unsigned int)u) << 16; return x.f;
}
__device__ __forceinline__ u16 f2bf(float f) {
    __hip_bfloat16 b = __float2bfloat16(f);
    return *(u16*)&b;
}
// gelu(x) = 0.5x(1+tanh(z)), z=0.79788456(x+0.044715x^3)  ==  x / (1+e^{-2z})
__device__ __forceinline__ float gelu_fast(float x) {
    float e = __expf(x * (-1.5957691216057308f - 0.0713548162726009f * x * x));
    return x * __builtin_amdgcn_rcpf(1.f + e);
}
__device__ __forceinline__ void store_out(float* p, float v) { *p = v; }
__device__ __forceinline__ void store_out(u16* p, float v) { *p = f2bf(v); }
__device__ __forceinline__ void store_pair(float* p, float a, float b) {
    *(float2*)p = make_float2(a, b);
}
__device__ __forceinline__ void store_pair(u16* p, float a, float b) {
    unsigned int u = ((unsigned int)f2bf(b) << 16) | (unsigned int)f2bf(a);
    *(unsigned int*)p = u;
}

__device__ __forceinline__ void gl_lds16(const void* g, void* l) {
    __builtin_amdgcn_global_load_lds(
        (__attribute__((address_space(1))) void*)g,
        (__attribute__((address_space(3))) void*)l, 16, 0, 0);
}

// ---------------------------------------------------------------------------
__global__ __launch_bounds__(128) void embed_kernel(
        const int* __restrict__ tok, const float* __restrict__ emb,
        float* __restrict__ X, float* __restrict__ maskf) {
    int row = blockIdx.x;
    int t = threadIdx.x;
    int id = tok[row];
    if (t == 0) maskf[row] = (id > 0) ? 1.f : 0.f;
    int s = row & (SEQ - 1);
    int e0 = t * 4;
    float4 u = *(const float4*)(emb + (size_t)id * EMB + e0);
    float vals[4] = { u.x, u.y, u.z, u.w };
    float out[4];
#pragma unroll
    for (int j = 0; j < 4; ++j) {
        int ee = e0 + j;
        int i = ee >> 1;
        float div = expf(-0.035977892078031970f * (float)i);
        float ang = (float)s * div;
        float pe = (ee & 1) ? cosf(ang) : sinf(ang);
        out[j] = vals[j] + pe;
    }
    *(float4*)(X + (size_t)row * EMB + e0) = make_float4(out[0], out[1], out[2], out[3]);
}

// ---------------------------------------------------------------------------
// LN row kernel, vectorized (G13): float2 loads of x/sc/bi, packed 4B stores.
// ---------------------------------------------------------------------------
template<typename OUT>
__global__ __launch_bounds__(256) void ln_kernel(
        const float* __restrict__ X, const float* __restrict__ sc,
        const float* __restrict__ bi, OUT* __restrict__ Y) {
    int row = blockIdx.x, t = threadIdx.x;
    const float* x = X + (size_t)row * EMB;
    float2 v = *(const float2*)(x + 2 * t);
    float a = v.x, b = v.y;
    float s = a + b, q = a * a + b * b;
#pragma unroll
    for (int off = 32; off; off >>= 1) {
        s += __shfl_xor(s, off);
        q += __shfl_xor(q, off);
    }
    __shared__ float ss[4], qq[4];
    int w = t >> 6;
    if ((t & 63) == 0) { ss[w] = s; qq[w] = q; }
    __syncthreads();
    s = ss[0] + ss[1] + ss[2] + ss[3];
    q = qq[0] + qq[1] + qq[2] + qq[3];
    float mu = s * (1.f / 512.f);
    float var = q * (1.f / 512.f) - mu * mu;
    float rstd = rsqrtf(var + 1e-6f);
    float2 scv = *(const float2*)(sc + 2 * t);
    float2 biv = *(const float2*)(bi + 2 * t);
    float y0 = (a - mu) * rstd * scv.x + biv.x;
    float y1 = (b - mu) * rstd * scv.y + biv.y;
    store_pair(&Y[(size_t)row * EMB + 2 * t], y0, y1);
}

// ---------------------------------------------------------------------------
// Weight transpose + bf16 cast: W[K][N] f32 -> WT[N][K] bf16; z picks source
// ---------------------------------------------------------------------------
__global__ __launch_bounds__(256) void transpose_w(
        const float* __restrict__ W0, const float* __restrict__ W1,
        const float* __restrict__ W2, const float* __restrict__ W3,
        u16* __restrict__ WT, int K, int N) {
    const float* W = (blockIdx.z == 0) ? W0 : (blockIdx.z == 1) ? W1
                   : (blockIdx.z == 2) ? W2 : W3;
    u16* dst = WT + (size_t)blockIdx.z * K * N;
    __shared__ u16 tile[32][33];
    int n0 = blockIdx.x * 32, k0 = blockIdx.y * 32;
    int tx = threadIdx.x & 31, ty = threadIdx.x >> 5;
#pragma unroll
    for (int u = 0; u < 4; ++u)
        tile[ty + u * 8][tx] = f2bf(W[(size_t)(k0 + ty + u * 8) * N + n0 + tx]);
    __syncthreads();
#pragma unroll
    for (int u = 0; u < 4; ++u)
        dst[(size_t)(n0 + ty + u * 8) * K + k0 + tx] = tile[tx][ty + u * 8];
}

// ---------------------------------------------------------------------------
// MFMA bf16 GEMM: C[M,.] = epi(A[M,K]bf16 . BT[N,K]bf16^T)
// Tile 128(M) x 128(N), 4 waves each own a 64x64 quadrant (acc 4x4 of
// 16x16x32).  K-loop: stage-early double-buffer, BK=32 per buffer (32 KB
// LDS), issue next tile's global_load_lds BEFORE compute, one __syncthreads
// per step.  [r6: counted-vmcnt 3-buffer raw-barrier REGRESSED -- regime
// gate; this is the measured-best 2-phase config.]
// __launch_bounds__(256,4): LDS 32KB allows 5 blocks/CU; 4 waves/EU cap
// (128 VGPR/wave) fits acc(64)+temps without spills.  r7 ran (256,2) ->
// Occupancy pinned at 29%; barrier-drain hiding needs resident waves (m114).
// XCD-chunked block swizzle (bijective when nwg%8==0): FETCH 69->21 MB (r5).
// OP: 0=none, 1=gelu, 3=fused-qkv (seg by col0: q=phi, k=phi*mask, v=none).
// epi: (+bias) -> OP -> (+residual), residual loads staged before stores
// (residual may alias C; per-element single-owner load-then-store).
// ---------------------------------------------------------------------------
template<int OP, typename OUT>
__global__ __launch_bounds__(256, 4) void mfma_gemm(
        const u16* __restrict__ A, const u16* __restrict__ BT,
        const float* __restrict__ bias, const float* __restrict__ rowscale,
        const float* __restrict__ residual, OUT* __restrict__ C,
        int K, int lda, int ldb, int ldc) {
    __shared__ u16 As[2][128 * 32];   // buffer bb: [128 rows][32 k] (64B rows)
    __shared__ u16 Bs[2][128 * 32];
    int tid = threadIdx.x;
    int wid = tid >> 6, lane = tid & 63;
    // XCD swizzle (bijective when nwg % 8 == 0; else identity)
    int nwg = gridDim.x * gridDim.y;
    int lin = blockIdx.y * gridDim.x + blockIdx.x;
    int swz = (nwg & 7) ? lin : ((lin & 7) * (nwg >> 3) + (lin >> 3));
    int bx = swz % gridDim.x, by = swz / gridDim.x;
    int row0 = by * 128, col0 = bx * 128;
    int wm = (wid & 1) * 64, wn = (wid >> 1) * 64;
    int quad = lane >> 4, l16 = lane & 15;

    f32x4 acc[4][4];
#pragma unroll
    for (int i = 0; i < 4; ++i)
#pragma unroll
        for (int j = 0; j < 4; ++j)
#pragma unroll
            for (int r = 0; r < 4; ++r) acc[i][j][r] = 0.f;

    // staging: issue i covers rows i*64..i*64+63; wave w covers rows w*16 +
    // lane/4, 16B piece (lane&3).  LDS dest = wave-uniform base + lane*16.
    int rsub = lane >> 2;
    int koff = (lane & 3) * 8;
    const u16* gA = A  + (size_t)(row0 + wid * 16 + rsub) * lda + koff;
    const u16* gB = BT + (size_t)(col0 + wid * 16 + rsub) * ldb + koff;

    auto stage = [&](int bb, int kk) {
        u16* lA = As[bb] + wid * 512;
        u16* lB = Bs[bb] + wid * 512;
#pragma unroll
        for (int i = 0; i < 2; ++i) {
            gl_lds16(gA + (size_t)(i * 64) * lda + kk, lA + i * 2048);
            gl_lds16(gB + (size_t)(i * 64) * ldb + kk, lB + i * 2048);
        }
    };

    int nt = K >> 5;           // BK=32 steps
    stage(0, 0);
    __syncthreads();           // drain prologue loads
    for (int t = 0; t < nt; ++t) {
        int cur = t & 1;
        if (t + 1 < nt) stage(cur ^ 1, (t + 1) * 32);   // issue next tile EARLY
        bf16x8 af[4], bfv[4];
#pragma unroll
        for (int i = 0; i < 4; ++i)
            af[i] = *(const bf16x8*)(As[cur] + (wm + i * 16 + l16) * 32 + quad * 8);
#pragma unroll
        for (int j = 0; j < 4; ++j)
            bfv[j] = *(const bf16x8*)(Bs[cur] + (wn + j * 16 + l16) * 32 + quad * 8);
#pragma unroll
        for (int i = 0; i < 4; ++i)
#pragma unroll
            for (int j = 0; j < 4; ++j)
                acc[i][j] = __builtin_amdgcn_mfma_f32_16x16x32_bf16(af[i], bfv[j], acc[i][j], 0, 0, 0);
        __syncthreads();       // one barrier/step: drains next-tile vmcnt,
                               // fences LDS reuse for the other buffer
    }

    // epilogue: D mapping col = lane&15, row = quad*4 + reg (m89-verified)
    int seg = col0 >> 9;   // OP3: 0=q 1=k 2=v (128-col tile never straddles)
    float bc[4];
#pragma unroll
    for (int j = 0; j < 4; ++j)
        bc[j] = bias ? bias[col0 + wn + j * 16 + l16] : 0.f;
#pragma unroll
    for (int i = 0; i < 4; ++i) {
        // stage residual loads for this i-group (16 loads in flight, no
        // interleaved stores -> no alias-serialization)
        float res[4][4];
        if (residual) {
#pragma unroll
            for (int r = 0; r < 4; ++r) {
                size_t rb = (size_t)(row0 + wm + i * 16 + quad * 4 + r) * ldc + col0 + wn;
#pragma unroll
                for (int j = 0; j < 4; ++j)
                    res[r][j] = residual[rb + j * 16 + l16];
            }
        }
#pragma unroll
        for (int r = 0; r < 4; ++r) {
            int row = row0 + wm + i * 16 + quad * 4 + r;
            float rsv = (OP == 3 && seg == 1) ? rowscale[row] : 1.f;
            size_t rb = (size_t)row * ldc + col0 + wn;
#pragma unroll
            for (int j = 0; j < 4; ++j) {
                float val = acc[i][j][r] + bc[j];
                if (OP == 1) val = gelu_fast(val);
                if (OP == 3 && seg < 2) val = fmaxf(val, 0.f) + 1e-3f;
                if (OP == 3 && seg == 1) val *= rsv;
                size_t idx = rb + j * 16 + l16;
                if (residual) val += res[r][j];
                store_out(&C[idx], val);
            }
        }
    }
}

// ---------------------------------------------------------------------------
// MFMA kv-reduce: kv[bh][m][d] = sum_s PK[s][m]*V[s][d]; z[bh][m] = sum_s PK[s][m]
//   = GEMM PK^T . V with K = S.  Block: 4 waves, each owns a 32m x 32d quadrant
// (acc 2x2 of 16x16x32).  Per 32-s step: stage PK/V tiles [32][68] u16 padded,
// gather fragments with 8 scalar LDS reads each, 4 MFMA/wave.  z folded in as
// ones-operand MFMA on waves 0/1.  Prefetch next tile into regs pre-compute.
// grid = (32 bh, SEQ/256); atomics into zeroed KV/Z.
// ---------------------------------------------------------------------------
__global__ __launch_bounds__(256) void kv_reduce_mfma(
        const u16* __restrict__ PK, const u16* __restrict__ V,
        float* __restrict__ KV, float* __restrict__ Z, int ld) {
    __shared__ __align__(16) u16 pks[32][68];
    __shared__ __align__(16) u16 vvs[32][68];
    int bh = blockIdx.x;
    int b = bh >> 3, hh = bh & 7;
    int cc = blockIdx.y;
    int t = threadIdx.x;
    int wid = t >> 6, lane = t & 63;
    int quad = lane >> 4, l16 = lane & 15;
    int wm = (wid & 1) * 32, wd = (wid >> 1) * 32;

    f32x4 acc[2][2];
    f32x4 zacc[2];
#pragma unroll
    for (int i = 0; i < 2; ++i) {
#pragma unroll
        for (int j = 0; j < 2; ++j)
#pragma unroll
            for (int r = 0; r < 4; ++r) acc[i][j][r] = 0.f;
#pragma unroll
        for (int r = 0; r < 4; ++r) zacc[i][r] = 0.f;
    }
    bf16x8 ones;
#pragma unroll
    for (int e = 0; e < 8; ++e) ones[e] = (short)0x3F80;   // bf16 1.0

    // staging assignment: thread t -> row s_l = t>>3, 8-col piece mo = (t&7)*8
    int s_l = t >> 3, mo = (t & 7) * 8;
    const u16* gP = PK + (size_t)(b * SEQ + cc * 256 + s_l) * ld + hh * 64 + mo;
    const u16* gV = V  + (size_t)(b * SEQ + cc * 256 + s_l) * ld + hh * 64 + mo;
    ushort4 p0 = *(const ushort4*)gP;
    ushort4 p1 = *(const ushort4*)(gP + 4);
    ushort4 q0 = *(const ushort4*)gV;
    ushort4 q1 = *(const ushort4*)(gV + 4);

    for (int st = 0; st < 8; ++st) {
        *(ushort4*)&pks[s_l][mo]     = p0;
        *(ushort4*)&pks[s_l][mo + 4] = p1;
        *(ushort4*)&vvs[s_l][mo]     = q0;
        *(ushort4*)&vvs[s_l][mo + 4] = q1;
        __syncthreads();
        if (st < 7) {   // prefetch next tile (hides L2 latency under compute)
            gP += (size_t)32 * ld;  gV += (size_t)32 * ld;
            p0 = *(const ushort4*)gP;  p1 = *(const ushort4*)(gP + 4);
            q0 = *(const ushort4*)gV;  q1 = *(const ushort4*)(gV + 4);
        }
        bf16x8 af[2], bfv[2];
#pragma unroll
        for (int i = 0; i < 2; ++i) {
#pragma unroll
            for (int e = 0; e < 8; ++e) {
                af[i][e]  = (short)pks[quad * 8 + e][wm + i * 16 + l16];
                bfv[i][e] = (short)vvs[quad * 8 + e][wd + i * 16 + l16];
            }
        }
#pragma unroll
        for (int i = 0; i < 2; ++i)
#pragma unroll
            for (int j = 0; j < 2; ++j)
                acc[i][j] = __builtin_amdgcn_mfma_f32_16x16x32_bf16(af[i], bfv[j], acc[i][j], 0, 0, 0);
        if (wid < 2) {   // z: waves 0 (m 0..31) and 1 (m 32..63)
            zacc[0] = __builtin_amdgcn_mfma_f32_16x16x32_bf16(af[0], ones, zacc[0], 0, 0, 0);
            zacc[1] = __builtin_amdgcn_mfma_f32_16x16x32_bf16(af[1], ones, zacc[1], 0, 0, 0);
        }
        __syncthreads();
    }

    // epilogue: D col = l16, row = quad*4 + r
#pragma unroll
    for (int i = 0; i < 2; ++i)
#pragma unroll
        for (int j = 0; j < 2; ++j)
#pragma unroll
            for (int r = 0; r < 4; ++r)
                atomicAdd(&KV[((size_t)bh * 64 + wm + i * 16 + quad * 4 + r) * 64
                              + wd + j * 16 + l16], acc[i][j][r]);
    if (wid < 2 && l16 == 0) {
#pragma unroll
        for (int i = 0; i < 2; ++i)
#pragma unroll
            for (int r = 0; r < 4; ++r)
                atomicAdd(&Z[(size_t)bh * 64 + wm + i * 16 + quad * 4 + r], zacc[i][r]);
    }
}

// ---------------------------------------------------------------------------
// out[b,s,h,d] = (phi_q . kv[:,d]) / (phi_q . z);  PQ strided by ld
// ---------------------------------------------------------------------------
__global__ __launch_bounds__(256) void attn_out2(
        const u16* __restrict__ PQ, const float* __restrict__ KV,
        const float* __restrict__ Z, u16* __restrict__ O, int ld) {
    __shared__ float kvT[64 * 65];
    __shared__ float zsh[64];
    __shared__ float phs[4][72];
    int hh = blockIdx.y;
    int row0 = blockIdx.x * 32;
    int b = row0 >> 12;
    int bh = b * NH + hh;
    int t = threadIdx.x;
    const float* kvg = KV + (size_t)bh * 4096;
#pragma unroll
    for (int u = 0; u < 16; ++u) {
        int idx = u * 256 + t;
        kvT[(idx & 63) * 65 + (idx >> 6)] = kvg[idx];
    }
    if (t < 64) zsh[t] = Z[(size_t)bh * 64 + t];
    __syncthreads();
    int wid = t >> 6, lane = t & 63;
    const float* kvrow = kvT + lane * 65;
    for (int rr = 0; rr < 8; ++rr) {
        int row = row0 + wid * 8 + rr;
        float p = bf2f(PQ[(size_t)row * ld + hh * 64 + lane]);
        float d = p * zsh[lane];
#pragma unroll
        for (int off = 32; off; off >>= 1) d += __shfl_xor(d, off);
        d = fmaxf(d, 1e-20f);
        phs[wid][lane] = p;
        float acc = 0.f;
#pragma unroll
        for (int mm = 0; mm < 64; ++mm)
            acc = fmaf(phs[wid][mm], kvrow[mm], acc);
        O[(size_t)row * EMB + hh * 64 + lane] = f2bf(acc / d);
    }
}

// ---------------------------------------------------------------------------
extern "C" void kernel_launch(void* const* d_in, const int* in_sizes, int n_in,
                              void* d_out, int out_size, void* d_ws, size_t ws_size,
                              hipStream_t stream) {
    (void)in_sizes; (void)n_in; (void)out_size; (void)ws_size;
    const int*   tok  = (const int*)d_in[0];
    const float* emb  = (const float*)d_in[1];
    const float* ln1s = (const float*)d_in[2];
    const float* ln1b = (const float*)d_in[3];
    const float* wq   = (const float*)d_in[4];
    const float* wk   = (const float*)d_in[5];
    const float* wv   = (const float*)d_in[6];
    const float* wo   = (const float*)d_in[7];
    const float* ln2s = (const float*)d_in[8];
    const float* ln2b = (const float*)d_in[9];
    const float* w1   = (const float*)d_in[10];
    const float* b1   = (const float*)d_in[11];
    const float* w2   = (const float*)d_in[12];
    const float* b2   = (const float*)d_in[13];
    const float* lnfs = (const float*)d_in[14];
    const float* lnfb = (const float*)d_in[15];

    char* ws = (char*)d_ws;
    const size_t MB = 1024 * 1024;
    float* x    = (float*)(ws);                    // [BS,512] f32 residual, 0-32MB
    u16*   h    = (u16*)(ws + 32 * MB);            // [BS,512] bf16, 32-48
    u16*   qkv  = (u16*)(ws + 48 * MB);            // [BS,1536] bf16, 48-96
    u16*   m    = qkv;                             // [BS,2048] FFN buf aliases qkv, 48-112
    float* kv   = (float*)(ws + 112 * MB);         // [B,H,64,64]
    float* z    = kv + BATCH * NH * HD * HD;
    float* maskf = (float*)(ws + 112 * MB + 768 * 1024);  // [BS]
    u16*   wt   = (u16*)(ws + 113 * MB);           // qkvoT: 4x[512][512] (2MB)
    u16*   w1t  = (u16*)(ws + 115 * MB);           // w1T [2048][512] (2MB)
    u16*   w2t  = (u16*)(ws + 117 * MB);           // w2T [512][2048] (2MB)
    // layout end: 119 MB

    embed_kernel<<<BS_TOK, 128, 0, stream>>>(tok, emb, x, maskf);

    const size_t WSTEP = (size_t)EMB * EMB;
    dim3 gQKV(12, BS_TOK / 128);    // N=1536, nwg=1536 (%8==0)
    dim3 gN512(4, BS_TOK / 128);    // N=512,  nwg=512
    dim3 gN2048(16, BS_TOK / 128);  // N=2048, nwg=2048

    for (int l = 0; l < NL; ++l) {
        ln_kernel<u16><<<BS_TOK, 256, 0, stream>>>(x, ln1s + l * EMB, ln1b + l * EMB, h);
        // transpose wq,wk,wv,wo -> wt slots 0..3
        transpose_w<<<dim3(16, 16, 4), 256, 0, stream>>>(
            wq + l * WSTEP, wk + l * WSTEP, wv + l * WSTEP, wo + l * WSTEP, wt, EMB, EMB);
        // fused qkv: q=phi, k=phi*mask, v=plain -> qkv [BS,1536]
        mfma_gemm<3, u16><<<gQKV, 256, 0, stream>>>(
            h, wt, nullptr, maskf, nullptr, qkv, EMB, EMB, EMB, 1536);

        hipMemsetAsync(kv, 0, (size_t)(BATCH * NH * HD * HD + BATCH * NH * HD) * sizeof(float), stream);
        kv_reduce_mfma<<<dim3(BATCH * NH, SEQ / 256), 256, 0, stream>>>(qkv + 512, qkv + 1024, kv, z, 1536);
        attn_out2<<<dim3(BS_TOK / 32, NH), 256, 0, stream>>>(qkv, kv, z, h, 1536);

        // x = x + attn_out @ wo
        mfma_gemm<0, float><<<gN512, 256, 0, stream>>>(
            h, wt + 3 * WSTEP, nullptr, nullptr, x, x, EMB, EMB, EMB, EMB);

        ln_kernel<u16><<<BS_TOK, 256, 0, stream>>>(x, ln2s + l * EMB, ln2b + l * EMB, h);
        const float* w1l = w1 + (size_t)l * EMB * FF;
        const float* w2l = w2 + (size_t)l * FF * EMB;
        const float* b1l = b1 + (size_t)l * FF;
        const float* b2l = b2 + (size_t)l * EMB;
        transpose_w<<<dim3(64, 16, 1), 256, 0, stream>>>(w1l, w1l, w1l, w1l, w1t, EMB, FF);  // [2048][512]
        transpose_w<<<dim3(16, 64, 1), 256, 0, stream>>>(w2l, w2l, w2l, w2l, w2t, FF, EMB);  // [512][2048]
        // merged FFN (r8): m = gelu(h @ w1 + b1) [BS,2048] in ONE dispatch;
        // x += m @ w2 + b2 in ONE K=2048 dispatch (was 2x K-split reading and
        // writing the 32MB f32 residual twice per layer).
        mfma_gemm<1, u16><<<gN2048, 256, 0, stream>>>(
            h, w1t, b1l, nullptr, nullptr, m, EMB, EMB, EMB, FF);
        mfma_gemm<0, float><<<gN512, 256, 0, stream>>>(
            m, w2t, b2l, nullptr, x, x, FF, FF, FF, EMB);
    }

    ln_kernel<float><<<BS_TOK, 256, 0, stream>>>(x, lnfs, lnfb, (float*)d_out);
}